// Round 1
// baseline (604.314 us; speedup 1.0000x reference)
//
#include <hip/hip_runtime.h>

#define IN 128
#define OUT 200
#define GROWS 16

// ---------------- graph preprocessing ----------------

__global__ void k_deg_cnt(const int* __restrict__ src, const int* __restrict__ dst,
                          const float* __restrict__ w, float* __restrict__ deg,
                          int* __restrict__ cnt, int E) {
  int e = blockIdx.x * blockDim.x + threadIdx.x;
  if (e >= E) return;
  atomicAdd(&deg[src[e]], w[e]);
  atomicAdd(&cnt[dst[e]], 1);
}

__global__ void k_dis(float* deg, int n) {
  int i = blockIdx.x * blockDim.x + threadIdx.x;
  if (i >= n) return;
  float d = deg[i];
  deg[i] = d > 0.f ? rsqrtf(d) : 0.f;  // in-place deg -> D^{-1/2}
}

__global__ void k_norm(const int* __restrict__ src, const int* __restrict__ dst,
                       const float* __restrict__ w, const float* __restrict__ dis,
                       float* __restrict__ norm, int E) {
  int e = blockIdx.x * blockDim.x + threadIdx.x;
  if (e >= E) return;
  norm[e] = -dis[src[e]] * w[e] * dis[dst[e]];
}

// ---------------- 2-level exclusive scan (N ~ 50k, 256/block) ----------------

__global__ void k_scan_a(const int* __restrict__ cnt, int* __restrict__ offs,
                         int* __restrict__ bsum, int n) {
  __shared__ int s[256];
  int t = threadIdx.x;
  int i = blockIdx.x * 256 + t;
  int v = (i < n) ? cnt[i] : 0;
  s[t] = v;
  __syncthreads();
  for (int o = 1; o < 256; o <<= 1) {
    int a = (t >= o) ? s[t - o] : 0;
    __syncthreads();
    s[t] += a;
    __syncthreads();
  }
  if (i < n) offs[i] = s[t] - v;           // exclusive within block
  if (t == 255) bsum[blockIdx.x] = s[255]; // block total
}

__global__ void k_scan_b(int* bsum, int nb) {  // nb <= 256
  __shared__ int s[256];
  int t = threadIdx.x;
  int v = (t < nb) ? bsum[t] : 0;
  s[t] = v;
  __syncthreads();
  for (int o = 1; o < 256; o <<= 1) {
    int a = (t >= o) ? s[t - o] : 0;
    __syncthreads();
    s[t] += a;
    __syncthreads();
  }
  if (t < nb) bsum[t] = s[t] - v;
}

__global__ void k_scan_c(int* __restrict__ offs, const int* __restrict__ bsum, int n, int E) {
  int i = blockIdx.x * 256 + threadIdx.x;
  if (i < n) offs[i] += bsum[blockIdx.x];
  if (i == 0) offs[n] = E;
}

__global__ void k_fill(const int* __restrict__ src, const int* __restrict__ dst,
                       const float* __restrict__ norm, const int* __restrict__ offs,
                       int* __restrict__ cursor, int* __restrict__ csr_src,
                       float* __restrict__ csr_norm, int E) {
  int e = blockIdx.x * blockDim.x + threadIdx.x;
  if (e >= E) return;
  int d = dst[e];
  int pos = offs[d] + atomicAdd(&cursor[d], 1);
  csr_src[pos] = src[e];
  csr_norm[pos] = norm[e];
}

// ---------------- gather-based propagation: out[i] = sum norm_p * h[src_p] ----------------

template <int MODE>
__global__ void k_gather(const float* __restrict__ h, const float* __restrict__ x,
                         const int* __restrict__ csr_src, const float* __restrict__ csr_norm,
                         const int* __restrict__ offs, float* __restrict__ out, int n) {
  int node = blockIdx.x;
  int ch = threadIdx.x;
  int s = offs[node], e = offs[node + 1];
  float acc = 0.f, acc2 = 0.f;
  int p = s;
  for (; p + 1 < e; p += 2) {
    int s0 = csr_src[p], s1 = csr_src[p + 1];
    float n0 = csr_norm[p], n1 = csr_norm[p + 1];
    acc  = fmaf(n0, h[(size_t)s0 * IN + ch], acc);
    acc2 = fmaf(n1, h[(size_t)s1 * IN + ch], acc2);
  }
  if (p < e) acc = fmaf(csr_norm[p], h[(size_t)csr_src[p] * IN + ch], acc);
  acc += acc2;
  if (MODE == 0)
    out[(size_t)node * IN + ch] = acc;                                  // tx1
  else
    out[(size_t)node * IN + ch] = 2.f * acc - x[(size_t)node * IN + ch]; // tx2 = 2*L tx1 - x
}

// ---------------- fused 6-way GEMM: s1,s2,s3 ----------------

__global__ __launch_bounds__(256) void k_gemm(
    const float* __restrict__ x, const float* __restrict__ tx1, const float* __restrict__ t2,
    const float* __restrict__ w10, const float* __restrict__ b1v,
    const float* __restrict__ w20, const float* __restrict__ w21, const float* __restrict__ b2v,
    const float* __restrict__ w30, const float* __restrict__ w31, const float* __restrict__ w32,
    const float* __restrict__ b3v, float* __restrict__ out, int n) {
  __shared__ float l0[GROWS][IN], l1[GROWS][IN], l2[GROWS][IN];
  int tid = threadIdx.x;
  long r0 = (long)blockIdx.x * GROWS;
  // stage 16 rows x 128 ch of all three operands (float4)
  for (int i = tid; i < GROWS * IN / 4; i += 256) {
    int r = i >> 5;          // IN/4 = 32 float4 per row
    int k = (i & 31) * 4;
    long row = r0 + r;
    float4 a, b, c;
    if (row < n) {
      a = *(const float4*)&x[row * IN + k];
      b = *(const float4*)&tx1[row * IN + k];
      c = *(const float4*)&t2[row * IN + k];
    } else {
      a = make_float4(0.f, 0.f, 0.f, 0.f); b = a; c = a;
    }
    *(float4*)&l0[r][k] = a;
    *(float4*)&l1[r][k] = b;
    *(float4*)&l2[r][k] = c;
  }
  __syncthreads();
  int c = tid;
  bool active = c < OUT;
  int cc = active ? c : 0;
  float acc1[GROWS], acc2[GROWS], acc3[GROWS];
  float bb1 = b1v[cc], bb2 = b2v[cc], bb3 = b3v[cc];
#pragma unroll
  for (int r = 0; r < GROWS; ++r) { acc1[r] = bb1; acc2[r] = bb2; acc3[r] = bb3; }

  for (int k4 = 0; k4 < IN; k4 += 4) {
    float wa[4], wb[4], wc[4], wd[4], we_[4], wf[4];
#pragma unroll
    for (int j = 0; j < 4; ++j) {
      int idx = (k4 + j) * OUT + cc;
      wa[j] = w10[idx]; wb[j] = w20[idx]; wc[j] = w21[idx];
      wd[j] = w30[idx]; we_[j] = w31[idx]; wf[j] = w32[idx];
    }
#pragma unroll
    for (int r = 0; r < GROWS; ++r) {
      float4 xv = *(const float4*)&l0[r][k4];
      float4 yv = *(const float4*)&l1[r][k4];
      float4 zv = *(const float4*)&l2[r][k4];
      float a1 = acc1[r], a2 = acc2[r], a3 = acc3[r];
      a1 = fmaf(xv.x, wa[0], a1); a1 = fmaf(xv.y, wa[1], a1);
      a1 = fmaf(xv.z, wa[2], a1); a1 = fmaf(xv.w, wa[3], a1);
      a2 = fmaf(xv.x, wb[0], a2); a2 = fmaf(xv.y, wb[1], a2);
      a2 = fmaf(xv.z, wb[2], a2); a2 = fmaf(xv.w, wb[3], a2);
      a2 = fmaf(yv.x, wc[0], a2); a2 = fmaf(yv.y, wc[1], a2);
      a2 = fmaf(yv.z, wc[2], a2); a2 = fmaf(yv.w, wc[3], a2);
      a3 = fmaf(xv.x, wd[0], a3); a3 = fmaf(xv.y, wd[1], a3);
      a3 = fmaf(xv.z, wd[2], a3); a3 = fmaf(xv.w, wd[3], a3);
      a3 = fmaf(yv.x, we_[0], a3); a3 = fmaf(yv.y, we_[1], a3);
      a3 = fmaf(yv.z, we_[2], a3); a3 = fmaf(yv.w, we_[3], a3);
      a3 = fmaf(zv.x, wf[0], a3); a3 = fmaf(zv.y, wf[1], a3);
      a3 = fmaf(zv.z, wf[2], a3); a3 = fmaf(zv.w, wf[3], a3);
      acc1[r] = a1; acc2[r] = a2; acc3[r] = a3;
    }
  }

  if (active) {
    long NS = (long)n * OUT;
    #pragma unroll
    for (int r = 0; r < GROWS; ++r) {
      long row = r0 + r;
      if (row < n) {
        out[row * OUT + c]          = acc1[r];
        out[NS + row * OUT + c]     = acc2[r];
        out[2 * NS + row * OUT + c] = acc3[r];
      }
    }
  }
}

// ---------------- launch ----------------

extern "C" void kernel_launch(void* const* d_in, const int* in_sizes, int n_in,
                              void* d_out, int out_size, void* d_ws, size_t ws_size,
                              hipStream_t stream) {
  const float* x   = (const float*)d_in[0];
  const int*   ei  = (const int*)d_in[1];
  const float* ew  = (const float*)d_in[2];
  const float* w10 = (const float*)d_in[3];
  const float* b1  = (const float*)d_in[4];
  const float* w20 = (const float*)d_in[5];
  const float* w21 = (const float*)d_in[6];
  const float* b2  = (const float*)d_in[7];
  const float* w30 = (const float*)d_in[8];
  const float* w31 = (const float*)d_in[9];
  const float* w32 = (const float*)d_in[10];
  const float* b3  = (const float*)d_in[11];
  float* out = (float*)d_out;

  int N = in_sizes[0] / IN;
  int E = in_sizes[2];
  const int* src = ei;
  const int* dst = ei + E;

  char* ws = (char*)d_ws;
  size_t off = 0;
  auto alloc = [&](size_t elems) { void* p = ws + off; off += elems * 4; return p; };
  float* deg      = (float*)alloc(N);       // becomes dis in place
  float* norm     = (float*)alloc(E);
  int*   cnt      = (int*)alloc(N);
  int*   offs     = (int*)alloc((size_t)N + 1);
  int*   cursor   = (int*)alloc(N);
  int*   csr_src  = (int*)alloc(E);
  float* csr_norm = (float*)alloc(E);
  int*   bsum     = (int*)alloc(256);
  off = (off + 15) & ~(size_t)15;
  float* tx1 = (float*)(ws + off); off += (size_t)N * IN * 4;
  float* t2  = (float*)(ws + off); off += (size_t)N * IN * 4;

  hipMemsetAsync(deg, 0, (size_t)N * 4, stream);
  hipMemsetAsync(cnt, 0, (size_t)N * 4, stream);
  hipMemsetAsync(cursor, 0, (size_t)N * 4, stream);

  const int tb = 256;
  int ge = (E + tb - 1) / tb;
  int gn = (N + tb - 1) / tb;
  int nb = (N + 255) / 256;  // 196 for N=50000, fits single-block scan_b

  k_deg_cnt<<<ge, tb, 0, stream>>>(src, dst, ew, deg, cnt, E);
  k_dis<<<gn, tb, 0, stream>>>(deg, N);
  k_norm<<<ge, tb, 0, stream>>>(src, dst, ew, deg, norm, E);
  k_scan_a<<<nb, 256, 0, stream>>>(cnt, offs, bsum, N);
  k_scan_b<<<1, 256, 0, stream>>>(bsum, nb);
  k_scan_c<<<nb, 256, 0, stream>>>(offs, bsum, N, E);
  k_fill<<<ge, tb, 0, stream>>>(src, dst, norm, offs, cursor, csr_src, csr_norm, E);
  k_gather<0><<<N, IN, 0, stream>>>(x, x, csr_src, csr_norm, offs, tx1, N);
  k_gather<1><<<N, IN, 0, stream>>>(tx1, x, csr_src, csr_norm, offs, t2, N);
  int gg = (N + GROWS - 1) / GROWS;
  k_gemm<<<gg, 256, 0, stream>>>(x, tx1, t2, w10, b1, w20, w21, b2, w30, w31, w32, b3, out, N);
}

// Round 2
// 348.711 us; speedup vs baseline: 1.7330x; 1.7330x over previous
//
#include <hip/hip_runtime.h>

#define IN 128
#define OUT 200
#define NT 13            // ceil(200/16) N-tiles
#define MT 128           // M rows per GEMM block

typedef __bf16 bf16x8 __attribute__((ext_vector_type(8)));
typedef float f32x4 __attribute__((ext_vector_type(4)));
typedef unsigned short ushort;
typedef ushort ushort8 __attribute__((ext_vector_type(8)));
typedef unsigned int uint;

__device__ inline ushort f2bf(float f) {          // RNE f32 -> bf16 bits
  uint b = __float_as_uint(f);
  return (ushort)((b + 0x7FFFu + ((b >> 16) & 1u)) >> 16);
}
__device__ inline float bf_lo(uint v) { return __uint_as_float(v << 16); }
__device__ inline float bf_hi(uint v) { return __uint_as_float(v & 0xFFFF0000u); }

// ---------------- graph preprocessing ----------------

__global__ void k_deg_cnt(const int* __restrict__ src, const int* __restrict__ dst,
                          const float* __restrict__ w, float* __restrict__ deg,
                          int* __restrict__ cnt, int E) {
  int e = blockIdx.x * blockDim.x + threadIdx.x;
  if (e >= E) return;
  atomicAdd(&deg[src[e]], w[e]);
  atomicAdd(&cnt[dst[e]], 1);
}

__global__ void k_dis(float* deg, int n) {
  int i = blockIdx.x * blockDim.x + threadIdx.x;
  if (i >= n) return;
  float d = deg[i];
  deg[i] = d > 0.f ? rsqrtf(d) : 0.f;
}

__global__ void k_norm(const int* __restrict__ src, const int* __restrict__ dst,
                       const float* __restrict__ w, const float* __restrict__ dis,
                       float* __restrict__ norm, int E) {
  int e = blockIdx.x * blockDim.x + threadIdx.x;
  if (e >= E) return;
  norm[e] = -dis[src[e]] * w[e] * dis[dst[e]];
}

__global__ void k_scan_a(const int* __restrict__ cnt, int* __restrict__ offs,
                         int* __restrict__ bsum, int n) {
  __shared__ int s[256];
  int t = threadIdx.x;
  int i = blockIdx.x * 256 + t;
  int v = (i < n) ? cnt[i] : 0;
  s[t] = v;
  __syncthreads();
  for (int o = 1; o < 256; o <<= 1) {
    int a = (t >= o) ? s[t - o] : 0;
    __syncthreads();
    s[t] += a;
    __syncthreads();
  }
  if (i < n) offs[i] = s[t] - v;
  if (t == 255) bsum[blockIdx.x] = s[255];
}

__global__ void k_scan_b(int* bsum, int nb) {
  __shared__ int s[256];
  int t = threadIdx.x;
  int v = (t < nb) ? bsum[t] : 0;
  s[t] = v;
  __syncthreads();
  for (int o = 1; o < 256; o <<= 1) {
    int a = (t >= o) ? s[t - o] : 0;
    __syncthreads();
    s[t] += a;
    __syncthreads();
  }
  if (t < nb) bsum[t] = s[t] - v;
}

__global__ void k_scan_c(int* __restrict__ offs, const int* __restrict__ bsum, int n, int E) {
  int i = blockIdx.x * 256 + threadIdx.x;
  if (i < n) offs[i] += bsum[blockIdx.x];
  if (i == 0) offs[n] = E;
}

__global__ void k_fill(const int* __restrict__ src, const int* __restrict__ dst,
                       const float* __restrict__ norm, const int* __restrict__ offs,
                       int* __restrict__ cursor, int* __restrict__ csr_src,
                       float* __restrict__ csr_norm, int E) {
  int e = blockIdx.x * blockDim.x + threadIdx.x;
  if (e >= E) return;
  int d = dst[e];
  int pos = offs[d] + atomicAdd(&cursor[d], 1);
  csr_src[pos] = src[e];
  csr_norm[pos] = norm[e];
}

// ---------------- x -> bf16 ----------------

__global__ void k_cast_x(const float* __restrict__ x, ushort* __restrict__ xb, long total) {
  long i = ((long)blockIdx.x * blockDim.x + threadIdx.x) * 8;
  if (i >= total) return;
  float4 a = *(const float4*)&x[i];
  float4 b = *(const float4*)&x[i + 4];
  ushort8 o;
  o[0] = f2bf(a.x); o[1] = f2bf(a.y); o[2] = f2bf(a.z); o[3] = f2bf(a.w);
  o[4] = f2bf(b.x); o[5] = f2bf(b.y); o[6] = f2bf(b.z); o[7] = f2bf(b.w);
  *(ushort8*)&xb[i] = o;
}

// ---------------- pack 6 weight matrices into MFMA B-fragment order ----------------
// frag id f = (m*NT + t)*4 + kk ; lane l ; elem j:
//   k = kk*32 + (l>>4)*8 + j ; col = t*16 + (l&15) ; value = col<OUT ? bf16(w[k*OUT+col]) : 0

__global__ void k_pack_w(const float* __restrict__ w10, const float* __restrict__ w20,
                         const float* __restrict__ w21, const float* __restrict__ w30,
                         const float* __restrict__ w31, const float* __restrict__ w32,
                         ushort* __restrict__ wpack) {
  int gid = blockIdx.x * blockDim.x + threadIdx.x;   // one thread per (frag,lane)
  int total = 6 * NT * 4 * 64;
  if (gid >= total) return;
  int lane = gid & 63;
  int f = gid >> 6;
  int kk = f & 3;
  int t = (f >> 2) % NT;
  int m = f / (4 * NT);
  const float* w = (m == 0) ? w10 : (m == 1) ? w20 : (m == 2) ? w21
                 : (m == 3) ? w30 : (m == 4) ? w31 : w32;
  int col = t * 16 + (lane & 15);
  int kbase = kk * 32 + (lane >> 4) * 8;
  ushort8 o;
#pragma unroll
  for (int j = 0; j < 8; ++j)
    o[j] = (col < OUT) ? f2bf(w[(kbase + j) * OUT + col]) : (ushort)0;
  *(ushort8*)&wpack[(size_t)gid * 8] = o;
}

// ---------------- gather propagation (bf16 in/out, fp32 accum) ----------------
// MODE 0: out = Lhat h      MODE 1: out = 2*Lhat h - x

template <int MODE>
__global__ void k_gather(const ushort* __restrict__ h, const ushort* __restrict__ xb,
                         const int* __restrict__ csr_src, const float* __restrict__ csr_norm,
                         const int* __restrict__ offs, ushort* __restrict__ out, int n) {
  int node = blockIdx.x * 4 + (threadIdx.x >> 6);
  if (node >= n) return;
  int ch0 = (threadIdx.x & 63) * 2;
  int s = offs[node], e = offs[node + 1];
  float a0 = 0.f, a1 = 0.f, b0 = 0.f, b1 = 0.f;
  int p = s;
  for (; p + 1 < e; p += 2) {
    int s0 = csr_src[p], s1 = csr_src[p + 1];
    float n0 = csr_norm[p], n1 = csr_norm[p + 1];
    uint v0 = *(const uint*)&h[(size_t)s0 * IN + ch0];
    uint v1 = *(const uint*)&h[(size_t)s1 * IN + ch0];
    a0 = fmaf(n0, bf_lo(v0), a0); a1 = fmaf(n0, bf_hi(v0), a1);
    b0 = fmaf(n1, bf_lo(v1), b0); b1 = fmaf(n1, bf_hi(v1), b1);
  }
  if (p < e) {
    float n0 = csr_norm[p];
    uint v0 = *(const uint*)&h[(size_t)csr_src[p] * IN + ch0];
    a0 = fmaf(n0, bf_lo(v0), a0); a1 = fmaf(n0, bf_hi(v0), a1);
  }
  float r0 = a0 + b0, r1 = a1 + b1;
  if (MODE == 1) {
    uint xv = *(const uint*)&xb[(size_t)node * IN + ch0];
    r0 = 2.f * r0 - bf_lo(xv);
    r1 = 2.f * r1 - bf_hi(xv);
  }
  uint packed = (uint)f2bf(r0) | ((uint)f2bf(r1) << 16);
  *(uint*)&out[(size_t)node * IN + ch0] = packed;
}

// ---------------- fused MFMA GEMM: s1,s2,s3 ----------------
// block = 256 thr (4 waves); wave w owns rows [blk*128 + w*32, +32) as two 16-row groups.
// A frag (16x32 bf16): lane l -> row = l&15, k = (l>>4)*8 + j
// B frag (32x16 bf16): lane l -> col = l&15, k = (l>>4)*8 + j   (pre-packed)
// C/D (16x16 f32):     lane l, reg r -> row = (l>>4)*4 + r, col = l&15   [m89]

__global__ __launch_bounds__(256) void k_gemm_mfma(
    const ushort* __restrict__ xb, const ushort* __restrict__ tx1b, const ushort* __restrict__ t2b,
    const ushort* __restrict__ wpack,
    const float* __restrict__ b1v, const float* __restrict__ b2v, const float* __restrict__ b3v,
    float* __restrict__ out, int n) {
  int lane = threadIdx.x & 63;
  int wave = threadIdx.x >> 6;
  int row0 = blockIdx.x * MT + wave * 32;

  // load A fragments: a[mat][g][kk]
  bf16x8 a[3][2][4];
  const ushort* mats[3] = {xb, tx1b, t2b};
#pragma unroll
  for (int g = 0; g < 2; ++g) {
    int row = row0 + g * 16 + (lane & 15);
    if (row >= n) row = n - 1;
    size_t base = (size_t)row * IN + (lane >> 4) * 8;
#pragma unroll
    for (int m = 0; m < 3; ++m) {
#pragma unroll
      for (int kk = 0; kk < 4; ++kk)
        a[m][g][kk] = __builtin_bit_cast(bf16x8, *(const ushort8*)&mats[m][base + kk * 32]);
    }
  }

  long NS = (long)n * OUT;
  float* out1 = out;
  float* out2 = out + NS;
  float* out3 = out + 2 * NS;

  for (int t = 0; t < NT; ++t) {
    int col = t * 16 + (lane & 15);
    bool colok = col < OUT;
    int colc = colok ? col : 0;

    // ---- s1 = x @ w10 + b1 ----
    {
      float bias = colok ? b1v[colc] : 0.f;
      f32x4 acc0 = {bias, bias, bias, bias}, acc1 = acc0;
#pragma unroll
      for (int kk = 0; kk < 4; ++kk) {
        bf16x8 b = __builtin_bit_cast(bf16x8,
            *(const ushort8*)&wpack[(((size_t)(0 * NT + t) * 4 + kk) * 64 + lane) * 8]);
        acc0 = __builtin_amdgcn_mfma_f32_16x16x32_bf16(a[0][0][kk], b, acc0, 0, 0, 0);
        acc1 = __builtin_amdgcn_mfma_f32_16x16x32_bf16(a[0][1][kk], b, acc1, 0, 0, 0);
      }
      if (colok) {
#pragma unroll
        for (int r = 0; r < 4; ++r) {
          int ra = row0 + (lane >> 4) * 4 + r;
          if (ra < n) out1[(long)ra * OUT + col] = acc0[r];
          int rb = ra + 16;
          if (rb < n) out1[(long)rb * OUT + col] = acc1[r];
        }
      }
    }
    // ---- s2 = x @ w20 + tx1 @ w21 + b2 ----
    {
      float bias = colok ? b2v[colc] : 0.f;
      f32x4 acc0 = {bias, bias, bias, bias}, acc1 = acc0;
#pragma unroll
      for (int kk = 0; kk < 4; ++kk) {
        bf16x8 b = __builtin_bit_cast(bf16x8,
            *(const ushort8*)&wpack[(((size_t)(1 * NT + t) * 4 + kk) * 64 + lane) * 8]);
        acc0 = __builtin_amdgcn_mfma_f32_16x16x32_bf16(a[0][0][kk], b, acc0, 0, 0, 0);
        acc1 = __builtin_amdgcn_mfma_f32_16x16x32_bf16(a[0][1][kk], b, acc1, 0, 0, 0);
      }
#pragma unroll
      for (int kk = 0; kk < 4; ++kk) {
        bf16x8 b = __builtin_bit_cast(bf16x8,
            *(const ushort8*)&wpack[(((size_t)(2 * NT + t) * 4 + kk) * 64 + lane) * 8]);
        acc0 = __builtin_amdgcn_mfma_f32_16x16x32_bf16(a[1][0][kk], b, acc0, 0, 0, 0);
        acc1 = __builtin_amdgcn_mfma_f32_16x16x32_bf16(a[1][1][kk], b, acc1, 0, 0, 0);
      }
      if (colok) {
#pragma unroll
        for (int r = 0; r < 4; ++r) {
          int ra = row0 + (lane >> 4) * 4 + r;
          if (ra < n) out2[(long)ra * OUT + col] = acc0[r];
          int rb = ra + 16;
          if (rb < n) out2[(long)rb * OUT + col] = acc1[r];
        }
      }
    }
    // ---- s3 = x @ w30 + tx1 @ w31 + tx2 @ w32 + b3 ----
    {
      float bias = colok ? b3v[colc] : 0.f;
      f32x4 acc0 = {bias, bias, bias, bias}, acc1 = acc0;
#pragma unroll
      for (int m = 0; m < 3; ++m) {
#pragma unroll
        for (int kk = 0; kk < 4; ++kk) {
          bf16x8 b = __builtin_bit_cast(bf16x8,
              *(const ushort8*)&wpack[(((size_t)((3 + m) * NT + t) * 4 + kk) * 64 + lane) * 8]);
          acc0 = __builtin_amdgcn_mfma_f32_16x16x32_bf16(a[m][0][kk], b, acc0, 0, 0, 0);
          acc1 = __builtin_amdgcn_mfma_f32_16x16x32_bf16(a[m][1][kk], b, acc1, 0, 0, 0);
        }
      }
      if (colok) {
#pragma unroll
        for (int r = 0; r < 4; ++r) {
          int ra = row0 + (lane >> 4) * 4 + r;
          if (ra < n) out3[(long)ra * OUT + col] = acc0[r];
          int rb = ra + 16;
          if (rb < n) out3[(long)rb * OUT + col] = acc1[r];
        }
      }
    }
  }
}

// ---------------- launch ----------------

extern "C" void kernel_launch(void* const* d_in, const int* in_sizes, int n_in,
                              void* d_out, int out_size, void* d_ws, size_t ws_size,
                              hipStream_t stream) {
  const float* x   = (const float*)d_in[0];
  const int*   ei  = (const int*)d_in[1];
  const float* ew  = (const float*)d_in[2];
  const float* w10 = (const float*)d_in[3];
  const float* b1  = (const float*)d_in[4];
  const float* w20 = (const float*)d_in[5];
  const float* w21 = (const float*)d_in[6];
  const float* b2  = (const float*)d_in[7];
  const float* w30 = (const float*)d_in[8];
  const float* w31 = (const float*)d_in[9];
  const float* w32 = (const float*)d_in[10];
  const float* b3  = (const float*)d_in[11];
  float* out = (float*)d_out;

  int N = in_sizes[0] / IN;
  int E = in_sizes[2];
  const int* src = ei;
  const int* dst = ei + E;

  char* ws = (char*)d_ws;
  size_t off = 0;
  auto alloc = [&](size_t bytes) {
    void* p = ws + off;
    off = (off + bytes + 15) & ~(size_t)15;
    return p;
  };
  float* deg      = (float*)alloc((size_t)N * 4);
  float* norm     = (float*)alloc((size_t)E * 4);
  int*   cnt      = (int*)alloc((size_t)N * 4);
  int*   offs     = (int*)alloc(((size_t)N + 1) * 4);
  int*   cursor   = (int*)alloc((size_t)N * 4);
  int*   csr_src  = (int*)alloc((size_t)E * 4);
  float* csr_norm = (float*)alloc((size_t)E * 4);
  int*   bsum     = (int*)alloc(256 * 4);
  ushort* xb      = (ushort*)alloc((size_t)N * IN * 2);
  ushort* tx1b    = (ushort*)alloc((size_t)N * IN * 2);
  ushort* t2b     = (ushort*)alloc((size_t)N * IN * 2);
  ushort* wpack   = (ushort*)alloc((size_t)6 * NT * 4 * 64 * 8 * 2);

  hipMemsetAsync(deg, 0, (size_t)N * 4, stream);
  hipMemsetAsync(cnt, 0, (size_t)N * 4, stream);
  hipMemsetAsync(cursor, 0, (size_t)N * 4, stream);

  const int tb = 256;
  int ge = (E + tb - 1) / tb;
  int gn = (N + tb - 1) / tb;
  int nb = (N + 255) / 256;

  k_deg_cnt<<<ge, tb, 0, stream>>>(src, dst, ew, deg, cnt, E);
  k_dis<<<gn, tb, 0, stream>>>(deg, N);
  k_norm<<<ge, tb, 0, stream>>>(src, dst, ew, deg, norm, E);
  k_scan_a<<<nb, 256, 0, stream>>>(cnt, offs, bsum, N);
  k_scan_b<<<1, 256, 0, stream>>>(bsum, nb);
  k_scan_c<<<nb, 256, 0, stream>>>(offs, bsum, N, E);
  k_fill<<<ge, tb, 0, stream>>>(src, dst, norm, offs, cursor, csr_src, csr_norm, E);

  long totx = (long)N * IN;
  k_cast_x<<<(int)((totx / 8 + tb - 1) / tb), tb, 0, stream>>>(x, xb, totx);
  int wp_total = 6 * NT * 4 * 64;
  k_pack_w<<<(wp_total + tb - 1) / tb, tb, 0, stream>>>(w10, w20, w21, w30, w31, w32, wpack);

  int gblk = (N + 3) / 4;
  k_gather<0><<<gblk, 256, 0, stream>>>(xb, xb, csr_src, csr_norm, offs, tx1b, N);
  k_gather<1><<<gblk, 256, 0, stream>>>(tx1b, xb, csr_src, csr_norm, offs, t2b, N);

  int gg = (N + MT - 1) / MT;
  k_gemm_mfma<<<gg, 256, 0, stream>>>(xb, tx1b, t2b, wpack, b1, b2, b3, out, N);
}

// Round 3
// 320.038 us; speedup vs baseline: 1.8883x; 1.0896x over previous
//
#include <hip/hip_runtime.h>

#define IN 128
#define OUT 200
#define NT 13            // ceil(200/16) col-tiles
#define MT 128           // M rows per GEMM block (4 waves x 32 rows)

typedef __bf16 bf16x8 __attribute__((ext_vector_type(8)));
typedef float f32x4 __attribute__((ext_vector_type(4)));
typedef unsigned short ushort;
typedef ushort ushort8 __attribute__((ext_vector_type(8)));
typedef unsigned int uint;

__device__ inline ushort f2bf(float f) {          // RNE f32 -> bf16 bits
  uint b = __float_as_uint(f);
  return (ushort)((b + 0x7FFFu + ((b >> 16) & 1u)) >> 16);
}
__device__ inline float bf_lo(uint v) { return __uint_as_float(v << 16); }
__device__ inline float bf_hi(uint v) { return __uint_as_float(v & 0xFFFF0000u); }

// ---------------- graph preprocessing ----------------

__global__ void k_deg_cnt(const int* __restrict__ src, const int* __restrict__ dst,
                          const float* __restrict__ w, float* __restrict__ deg,
                          int* __restrict__ cnt, int E) {
  int e = blockIdx.x * blockDim.x + threadIdx.x;
  if (e >= E) return;
  atomicAdd(&deg[src[e]], w[e]);
  atomicAdd(&cnt[dst[e]], 1);
}

__global__ void k_dis(float* deg, int n) {
  int i = blockIdx.x * blockDim.x + threadIdx.x;
  if (i >= n) return;
  float d = deg[i];
  deg[i] = d > 0.f ? rsqrtf(d) : 0.f;
}

__global__ void k_norm(const int* __restrict__ src, const int* __restrict__ dst,
                       const float* __restrict__ w, const float* __restrict__ dis,
                       float* __restrict__ norm, int E) {
  int e = blockIdx.x * blockDim.x + threadIdx.x;
  if (e >= E) return;
  norm[e] = -dis[src[e]] * w[e] * dis[dst[e]];
}

__global__ void k_scan_a(const int* __restrict__ cnt, int* __restrict__ offs,
                         int* __restrict__ bsum, int n) {
  __shared__ int s[256];
  int t = threadIdx.x;
  int i = blockIdx.x * 256 + t;
  int v = (i < n) ? cnt[i] : 0;
  s[t] = v;
  __syncthreads();
  for (int o = 1; o < 256; o <<= 1) {
    int a = (t >= o) ? s[t - o] : 0;
    __syncthreads();
    s[t] += a;
    __syncthreads();
  }
  if (i < n) offs[i] = s[t] - v;
  if (t == 255) bsum[blockIdx.x] = s[255];
}

__global__ void k_scan_b(int* bsum, int nb) {
  __shared__ int s[256];
  int t = threadIdx.x;
  int v = (t < nb) ? bsum[t] : 0;
  s[t] = v;
  __syncthreads();
  for (int o = 1; o < 256; o <<= 1) {
    int a = (t >= o) ? s[t - o] : 0;
    __syncthreads();
    s[t] += a;
    __syncthreads();
  }
  if (t < nb) bsum[t] = s[t] - v;
}

__global__ void k_scan_c(int* __restrict__ offs, const int* __restrict__ bsum, int n, int E) {
  int i = blockIdx.x * 256 + threadIdx.x;
  if (i < n) offs[i] += bsum[blockIdx.x];
  if (i == 0) offs[n] = E;
}

__global__ void k_fill(const int* __restrict__ src, const int* __restrict__ dst,
                       const float* __restrict__ norm, const int* __restrict__ offs,
                       int* __restrict__ cursor, int* __restrict__ csr_src,
                       float* __restrict__ csr_norm, int E) {
  int e = blockIdx.x * blockDim.x + threadIdx.x;
  if (e >= E) return;
  int d = dst[e];
  int pos = offs[d] + atomicAdd(&cursor[d], 1);
  csr_src[pos] = src[e];
  csr_norm[pos] = norm[e];
}

// ---------------- x -> bf16 ----------------

__global__ void k_cast_x(const float* __restrict__ x, ushort* __restrict__ xb, long total) {
  long i = ((long)blockIdx.x * blockDim.x + threadIdx.x) * 8;
  if (i >= total) return;
  float4 a = *(const float4*)&x[i];
  float4 b = *(const float4*)&x[i + 4];
  ushort8 o;
  o[0] = f2bf(a.x); o[1] = f2bf(a.y); o[2] = f2bf(a.z); o[3] = f2bf(a.w);
  o[4] = f2bf(b.x); o[5] = f2bf(b.y); o[6] = f2bf(b.z); o[7] = f2bf(b.w);
  *(ushort8*)&xb[i] = o;
}

// ---------------- pack 6 weight matrices into MFMA B-fragment order ----------------

__global__ void k_pack_w(const float* __restrict__ w10, const float* __restrict__ w20,
                         const float* __restrict__ w21, const float* __restrict__ w30,
                         const float* __restrict__ w31, const float* __restrict__ w32,
                         ushort* __restrict__ wpack) {
  int gid = blockIdx.x * blockDim.x + threadIdx.x;   // one thread per (frag,lane)
  int total = 6 * NT * 4 * 64;
  if (gid >= total) return;
  int lane = gid & 63;
  int f = gid >> 6;
  int kk = f & 3;
  int t = (f >> 2) % NT;
  int m = f / (4 * NT);
  const float* w = (m == 0) ? w10 : (m == 1) ? w20 : (m == 2) ? w21
                 : (m == 3) ? w30 : (m == 4) ? w31 : w32;
  int col = t * 16 + (lane & 15);
  int kbase = kk * 32 + (lane >> 4) * 8;
  ushort8 o;
#pragma unroll
  for (int j = 0; j < 8; ++j)
    o[j] = (col < OUT) ? f2bf(w[(kbase + j) * OUT + col]) : (ushort)0;
  *(ushort8*)&wpack[(size_t)gid * 8] = o;
}

// ---------------- gather propagation (bf16 in/out, fp32 accum) ----------------

template <int MODE>
__global__ void k_gather(const ushort* __restrict__ h, const ushort* __restrict__ xb,
                         const int* __restrict__ csr_src, const float* __restrict__ csr_norm,
                         const int* __restrict__ offs, ushort* __restrict__ out, int n) {
  int node = blockIdx.x * 4 + (threadIdx.x >> 6);
  if (node >= n) return;
  int ch0 = (threadIdx.x & 63) * 2;
  int s = offs[node], e = offs[node + 1];
  float a0 = 0.f, a1 = 0.f, b0 = 0.f, b1 = 0.f;
  float c0 = 0.f, c1 = 0.f, d0 = 0.f, d1 = 0.f;
  int p = s;
  for (; p + 3 < e; p += 4) {
    int s0 = csr_src[p], s1 = csr_src[p + 1], s2 = csr_src[p + 2], s3 = csr_src[p + 3];
    float n0 = csr_norm[p], n1 = csr_norm[p + 1], n2 = csr_norm[p + 2], n3 = csr_norm[p + 3];
    uint v0 = *(const uint*)&h[(size_t)s0 * IN + ch0];
    uint v1 = *(const uint*)&h[(size_t)s1 * IN + ch0];
    uint v2 = *(const uint*)&h[(size_t)s2 * IN + ch0];
    uint v3 = *(const uint*)&h[(size_t)s3 * IN + ch0];
    a0 = fmaf(n0, bf_lo(v0), a0); a1 = fmaf(n0, bf_hi(v0), a1);
    b0 = fmaf(n1, bf_lo(v1), b0); b1 = fmaf(n1, bf_hi(v1), b1);
    c0 = fmaf(n2, bf_lo(v2), c0); c1 = fmaf(n2, bf_hi(v2), c1);
    d0 = fmaf(n3, bf_lo(v3), d0); d1 = fmaf(n3, bf_hi(v3), d1);
  }
  for (; p < e; ++p) {
    float n0 = csr_norm[p];
    uint v0 = *(const uint*)&h[(size_t)csr_src[p] * IN + ch0];
    a0 = fmaf(n0, bf_lo(v0), a0); a1 = fmaf(n0, bf_hi(v0), a1);
  }
  float r0 = (a0 + b0) + (c0 + d0);
  float r1 = (a1 + b1) + (c1 + d1);
  if (MODE == 1) {
    uint xv = *(const uint*)&xb[(size_t)node * IN + ch0];
    r0 = 2.f * r0 - bf_lo(xv);
    r1 = 2.f * r1 - bf_hi(xv);
  }
  uint packed = (uint)f2bf(r0) | ((uint)f2bf(r1) << 16);
  *(uint*)&out[(size_t)node * IN + ch0] = packed;
}

// ---------------- fused MFMA GEMM: s1,s2,s3 ----------------
// grid = (M-tiles, 7 col-tile-pairs); block = 256 (4 waves x 32 rows).
// A frag (16x32 bf16): lane l -> row = l&15, k = (l>>4)*8 + j
// B frag (32x16 bf16): lane l -> col = l&15, k = (l>>4)*8 + j   (pre-packed)
// C/D (16x16 f32):     lane l, reg r -> row = (l>>4)*4 + r, col = l&15

__global__ __launch_bounds__(256) void k_gemm_mfma(
    const ushort* __restrict__ xb, const ushort* __restrict__ tx1b, const ushort* __restrict__ t2b,
    const ushort* __restrict__ wpack,
    const float* __restrict__ b1v, const float* __restrict__ b2v, const float* __restrict__ b3v,
    float* __restrict__ out, int n) {
  int lane = threadIdx.x & 63;
  int wave = threadIdx.x >> 6;
  int row0 = blockIdx.x * MT + wave * 32;

  // load A fragments: a[mat][g][kk]
  bf16x8 a[3][2][4];
  const ushort* mats[3] = {xb, tx1b, t2b};
#pragma unroll
  for (int g = 0; g < 2; ++g) {
    int row = row0 + g * 16 + (lane & 15);
    if (row >= n) row = n - 1;
    size_t base = (size_t)row * IN + (lane >> 4) * 8;
#pragma unroll
    for (int m = 0; m < 3; ++m) {
#pragma unroll
      for (int kk = 0; kk < 4; ++kk)
        a[m][g][kk] = __builtin_bit_cast(bf16x8, *(const ushort8*)&mats[m][base + kk * 32]);
    }
  }

  long NS = (long)n * OUT;
  float* out1 = out;
  float* out2 = out + NS;
  float* out3 = out + 2 * NS;

#pragma unroll
  for (int ti = 0; ti < 2; ++ti) {
    int t = blockIdx.y * 2 + ti;
    if (t >= NT) break;
    int col = t * 16 + (lane & 15);
    bool colok = col < OUT;
    int colc = colok ? col : 0;

    // ---- s1 = x @ w10 + b1 ----
    {
      float bias = colok ? b1v[colc] : 0.f;
      f32x4 acc0 = {bias, bias, bias, bias}, acc1 = acc0;
#pragma unroll
      for (int kk = 0; kk < 4; ++kk) {
        bf16x8 b = __builtin_bit_cast(bf16x8,
            *(const ushort8*)&wpack[(((size_t)(0 * NT + t) * 4 + kk) * 64 + lane) * 8]);
        acc0 = __builtin_amdgcn_mfma_f32_16x16x32_bf16(a[0][0][kk], b, acc0, 0, 0, 0);
        acc1 = __builtin_amdgcn_mfma_f32_16x16x32_bf16(a[0][1][kk], b, acc1, 0, 0, 0);
      }
      if (colok) {
#pragma unroll
        for (int r = 0; r < 4; ++r) {
          int ra = row0 + (lane >> 4) * 4 + r;
          if (ra < n) out1[(long)ra * OUT + col] = acc0[r];
          int rb = ra + 16;
          if (rb < n) out1[(long)rb * OUT + col] = acc1[r];
        }
      }
    }
    // ---- s2 = x @ w20 + tx1 @ w21 + b2 ----
    {
      float bias = colok ? b2v[colc] : 0.f;
      f32x4 acc0 = {bias, bias, bias, bias}, acc1 = acc0;
#pragma unroll
      for (int kk = 0; kk < 4; ++kk) {
        bf16x8 b = __builtin_bit_cast(bf16x8,
            *(const ushort8*)&wpack[(((size_t)(1 * NT + t) * 4 + kk) * 64 + lane) * 8]);
        acc0 = __builtin_amdgcn_mfma_f32_16x16x32_bf16(a[0][0][kk], b, acc0, 0, 0, 0);
        acc1 = __builtin_amdgcn_mfma_f32_16x16x32_bf16(a[0][1][kk], b, acc1, 0, 0, 0);
      }
#pragma unroll
      for (int kk = 0; kk < 4; ++kk) {
        bf16x8 b = __builtin_bit_cast(bf16x8,
            *(const ushort8*)&wpack[(((size_t)(2 * NT + t) * 4 + kk) * 64 + lane) * 8]);
        acc0 = __builtin_amdgcn_mfma_f32_16x16x32_bf16(a[1][0][kk], b, acc0, 0, 0, 0);
        acc1 = __builtin_amdgcn_mfma_f32_16x16x32_bf16(a[1][1][kk], b, acc1, 0, 0, 0);
      }
      if (colok) {
#pragma unroll
        for (int r = 0; r < 4; ++r) {
          int ra = row0 + (lane >> 4) * 4 + r;
          if (ra < n) out2[(long)ra * OUT + col] = acc0[r];
          int rb = ra + 16;
          if (rb < n) out2[(long)rb * OUT + col] = acc1[r];
        }
      }
    }
    // ---- s3 = x @ w30 + tx1 @ w31 + tx2 @ w32 + b3 ----
    {
      float bias = colok ? b3v[colc] : 0.f;
      f32x4 acc0 = {bias, bias, bias, bias}, acc1 = acc0;
#pragma unroll
      for (int m = 0; m < 3; ++m) {
#pragma unroll
        for (int kk = 0; kk < 4; ++kk) {
          bf16x8 b = __builtin_bit_cast(bf16x8,
              *(const ushort8*)&wpack[(((size_t)((3 + m) * NT + t) * 4 + kk) * 64 + lane) * 8]);
          acc0 = __builtin_amdgcn_mfma_f32_16x16x32_bf16(a[m][0][kk], b, acc0, 0, 0, 0);
          acc1 = __builtin_amdgcn_mfma_f32_16x16x32_bf16(a[m][1][kk], b, acc1, 0, 0, 0);
        }
      }
      if (colok) {
#pragma unroll
        for (int r = 0; r < 4; ++r) {
          int ra = row0 + (lane >> 4) * 4 + r;
          if (ra < n) out3[(long)ra * OUT + col] = acc0[r];
          int rb = ra + 16;
          if (rb < n) out3[(long)rb * OUT + col] = acc1[r];
        }
      }
    }
  }
}

// ---------------- launch ----------------

extern "C" void kernel_launch(void* const* d_in, const int* in_sizes, int n_in,
                              void* d_out, int out_size, void* d_ws, size_t ws_size,
                              hipStream_t stream) {
  const float* x   = (const float*)d_in[0];
  const int*   ei  = (const int*)d_in[1];
  const float* ew  = (const float*)d_in[2];
  const float* w10 = (const float*)d_in[3];
  const float* b1  = (const float*)d_in[4];
  const float* w20 = (const float*)d_in[5];
  const float* w21 = (const float*)d_in[6];
  const float* b2  = (const float*)d_in[7];
  const float* w30 = (const float*)d_in[8];
  const float* w31 = (const float*)d_in[9];
  const float* w32 = (const float*)d_in[10];
  const float* b3  = (const float*)d_in[11];
  float* out = (float*)d_out;

  int N = in_sizes[0] / IN;
  int E = in_sizes[2];
  const int* src = ei;
  const int* dst = ei + E;

  char* ws = (char*)d_ws;
  size_t off = 0;
  auto alloc = [&](size_t bytes) {
    void* p = ws + off;
    off = (off + bytes + 15) & ~(size_t)15;
    return p;
  };
  float* deg      = (float*)alloc((size_t)N * 4);
  float* norm     = (float*)alloc((size_t)E * 4);
  int*   cnt      = (int*)alloc((size_t)N * 4);
  int*   offs     = (int*)alloc(((size_t)N + 1) * 4);
  int*   cursor   = (int*)alloc((size_t)N * 4);
  int*   csr_src  = (int*)alloc((size_t)E * 4);
  float* csr_norm = (float*)alloc((size_t)E * 4);
  int*   bsum     = (int*)alloc(256 * 4);
  ushort* xb      = (ushort*)alloc((size_t)N * IN * 2);
  ushort* tx1b    = (ushort*)alloc((size_t)N * IN * 2);
  ushort* t2b     = (ushort*)alloc((size_t)N * IN * 2);
  ushort* wpack   = (ushort*)alloc((size_t)6 * NT * 4 * 64 * 8 * 2);

  hipMemsetAsync(deg, 0, (size_t)N * 4, stream);
  hipMemsetAsync(cnt, 0, (size_t)N * 4, stream);
  hipMemsetAsync(cursor, 0, (size_t)N * 4, stream);

  const int tb = 256;
  int ge = (E + tb - 1) / tb;
  int gn = (N + tb - 1) / tb;
  int nb = (N + 255) / 256;

  k_deg_cnt<<<ge, tb, 0, stream>>>(src, dst, ew, deg, cnt, E);
  k_dis<<<gn, tb, 0, stream>>>(deg, N);
  k_norm<<<ge, tb, 0, stream>>>(src, dst, ew, deg, norm, E);
  k_scan_a<<<nb, 256, 0, stream>>>(cnt, offs, bsum, N);
  k_scan_b<<<1, 256, 0, stream>>>(bsum, nb);
  k_scan_c<<<nb, 256, 0, stream>>>(offs, bsum, N, E);
  k_fill<<<ge, tb, 0, stream>>>(src, dst, norm, offs, cursor, csr_src, csr_norm, E);

  long totx = (long)N * IN;
  k_cast_x<<<(int)((totx / 8 + tb - 1) / tb), tb, 0, stream>>>(x, xb, totx);
  int wp_total = 6 * NT * 4 * 64;
  k_pack_w<<<(wp_total + tb - 1) / tb, tb, 0, stream>>>(w10, w20, w21, w30, w31, w32, wpack);

  int gblk = (N + 3) / 4;
  k_gather<0><<<gblk, 256, 0, stream>>>(xb, xb, csr_src, csr_norm, offs, tx1b, N);
  k_gather<1><<<gblk, 256, 0, stream>>>(tx1b, xb, csr_src, csr_norm, offs, t2b, N);

  dim3 gg((N + MT - 1) / MT, (NT + 1) / 2);
  k_gemm_mfma<<<gg, 256, 0, stream>>>(xb, tx1b, t2b, wpack, b1, b2, b3, out, N);
}

// Round 4
// 297.235 us; speedup vs baseline: 2.0331x; 1.0767x over previous
//
#include <hip/hip_runtime.h>

#define IN 128
#define OUT 200
#define NT 13            // ceil(200/16) col-tiles
#define MT 128           // M rows per GEMM block (4 waves x 32 rows)

typedef __bf16 bf16x8 __attribute__((ext_vector_type(8)));
typedef float f32x4 __attribute__((ext_vector_type(4)));
typedef unsigned short ushort;
typedef ushort ushort8 __attribute__((ext_vector_type(8)));
typedef unsigned int uint;

__device__ inline ushort f2bf(float f) {          // RNE f32 -> bf16 bits
  uint b = __float_as_uint(f);
  return (ushort)((b + 0x7FFFu + ((b >> 16) & 1u)) >> 16);
}
__device__ inline float bf_lo(uint v) { return __uint_as_float(v << 16); }
__device__ inline float bf_hi(uint v) { return __uint_as_float(v & 0xFFFF0000u); }

// packed A layout: for (row r, ch k): rt=r>>4, lr=r&15, kk=k>>5, hi=(k&31)>>3, j=k&7
// ushort index = ((rt*4 + kk)*64 + hi*16 + lr)*8 + j        (512 ushorts per (rt,kk) frag)
__device__ inline size_t pk_idx(int row, int ch) {
  int rt = row >> 4, lr = row & 15, kk = ch >> 5, hi = (ch & 31) >> 3;
  return ((size_t)(rt * 4 + kk) * 64 + hi * 16 + lr) * 8 + (ch & 7);
}

// ---------------- graph preprocessing ----------------

__global__ void k_deg_cnt(const int* __restrict__ src, const int* __restrict__ dst,
                          const float* __restrict__ w, float* __restrict__ deg,
                          int* __restrict__ cnt, int E) {
  int e = blockIdx.x * blockDim.x + threadIdx.x;
  if (e >= E) return;
  atomicAdd(&deg[src[e]], w[e]);
  atomicAdd(&cnt[dst[e]], 1);
}

// dis (in-place on deg) + block-level exclusive scan of cnt
__global__ void k_dis_scan(float* __restrict__ deg, const int* __restrict__ cnt,
                           int* __restrict__ offs, int* __restrict__ bsum, int n) {
  __shared__ int s[256];
  int t = threadIdx.x;
  int i = blockIdx.x * 256 + t;
  if (i < n) {
    float d = deg[i];
    deg[i] = d > 0.f ? rsqrtf(d) : 0.f;
  }
  int v = (i < n) ? cnt[i] : 0;
  s[t] = v;
  __syncthreads();
  for (int o = 1; o < 256; o <<= 1) {
    int a = (t >= o) ? s[t - o] : 0;
    __syncthreads();
    s[t] += a;
    __syncthreads();
  }
  if (i < n) offs[i] = s[t] - v;
  if (t == 255) bsum[blockIdx.x] = s[255];
}

__global__ void k_scan_b(int* bsum, int nb) {
  __shared__ int s[256];
  int t = threadIdx.x;
  int v = (t < nb) ? bsum[t] : 0;
  s[t] = v;
  __syncthreads();
  for (int o = 1; o < 256; o <<= 1) {
    int a = (t >= o) ? s[t - o] : 0;
    __syncthreads();
    s[t] += a;
    __syncthreads();
  }
  if (t < nb) bsum[t] = s[t] - v;
}

__global__ void k_scan_c(int* __restrict__ offs, const int* __restrict__ bsum, int n, int E) {
  int i = blockIdx.x * 256 + threadIdx.x;
  if (i < n) offs[i] += bsum[blockIdx.x];
  if (i == 0) offs[n] = E;
}

// fill CSR with norm computed inline: norm = -dis[src]*w*dis[dst]
__global__ void k_fill(const int* __restrict__ src, const int* __restrict__ dst,
                       const float* __restrict__ w, const float* __restrict__ dis,
                       const int* __restrict__ offs, int* __restrict__ cursor,
                       int* __restrict__ csr_src, float* __restrict__ csr_norm, int E) {
  int e = blockIdx.x * blockDim.x + threadIdx.x;
  if (e >= E) return;
  int sN = src[e], d = dst[e];
  int pos = offs[d] + atomicAdd(&cursor[d], 1);
  csr_src[pos] = sN;
  csr_norm[pos] = -dis[sN] * w[e] * dis[d];
}

// ---------------- fused cast(x) + pack(weights) ----------------
// blocks [0, cast_blocks): cast x -> xb linear + xp packed
// blocks [cast_blocks, ...): pack 6 weight mats into MFMA B-frag order

__global__ void k_cast_pack(const float* __restrict__ x, ushort* __restrict__ xb,
                            ushort* __restrict__ xp, int cast_blocks, long totx,
                            const float* __restrict__ w10, const float* __restrict__ w20,
                            const float* __restrict__ w21, const float* __restrict__ w30,
                            const float* __restrict__ w31, const float* __restrict__ w32,
                            ushort* __restrict__ wpack) {
  if (blockIdx.x < (unsigned)cast_blocks) {
    long i = ((long)blockIdx.x * blockDim.x + threadIdx.x) * 8;
    if (i >= totx) return;
    float4 a = *(const float4*)&x[i];
    float4 b = *(const float4*)&x[i + 4];
    ushort8 o;
    o[0] = f2bf(a.x); o[1] = f2bf(a.y); o[2] = f2bf(a.z); o[3] = f2bf(a.w);
    o[4] = f2bf(b.x); o[5] = f2bf(b.y); o[6] = f2bf(b.z); o[7] = f2bf(b.w);
    *(ushort8*)&xb[i] = o;
    int row = (int)(i >> 7), ch = (int)(i & 127);
    *(ushort8*)&xp[pk_idx(row, ch)] = o;   // pk_idx is 8-contiguous for ch%8==0
  } else {
    int gid = (blockIdx.x - cast_blocks) * blockDim.x + threadIdx.x;
    int total = 6 * NT * 4 * 64;
    if (gid >= total) return;
    int lane = gid & 63;
    int f = gid >> 6;
    int kk = f & 3;
    int t = (f >> 2) % NT;
    int m = f / (4 * NT);
    const float* w = (m == 0) ? w10 : (m == 1) ? w20 : (m == 2) ? w21
                   : (m == 3) ? w30 : (m == 4) ? w31 : w32;
    int col = t * 16 + (lane & 15);
    int kbase = kk * 32 + (lane >> 4) * 8;
    ushort8 o;
#pragma unroll
    for (int j = 0; j < 8; ++j)
      o[j] = (col < OUT) ? f2bf(w[(kbase + j) * OUT + col]) : (ushort)0;
    *(ushort8*)&wpack[(size_t)gid * 8] = o;
  }
}

// ---------------- gather propagation (bf16, fp32 accum, ILP 8) ----------------
// MODE 0: r = Lhat h       -> write linear + packed (tx1)
// MODE 1: r = 2*Lhat h - x -> write packed only     (tx2)

template <int MODE>
__global__ void k_gather(const ushort* __restrict__ h, const ushort* __restrict__ xb,
                         const int* __restrict__ csr_src, const float* __restrict__ csr_norm,
                         const int* __restrict__ offs, ushort* __restrict__ out_lin,
                         ushort* __restrict__ out_pk, int n) {
  int node = blockIdx.x * 4 + (threadIdx.x >> 6);
  if (node >= n) return;
  int lane = threadIdx.x & 63;
  int ch0 = lane * 2;
  int s = offs[node], e = offs[node + 1];
  float lo[8], hi[8];
#pragma unroll
  for (int q = 0; q < 8; ++q) { lo[q] = 0.f; hi[q] = 0.f; }
  int p = s;
  for (; p + 7 < e; p += 8) {
    int si[8]; float nm[8]; uint v[8];
#pragma unroll
    for (int q = 0; q < 8; ++q) { si[q] = csr_src[p + q]; nm[q] = csr_norm[p + q]; }
#pragma unroll
    for (int q = 0; q < 8; ++q) v[q] = *(const uint*)&h[(size_t)si[q] * IN + ch0];
#pragma unroll
    for (int q = 0; q < 8; ++q) {
      lo[q] = fmaf(nm[q], bf_lo(v[q]), lo[q]);
      hi[q] = fmaf(nm[q], bf_hi(v[q]), hi[q]);
    }
  }
  for (; p + 1 < e; p += 2) {
    int s0 = csr_src[p], s1 = csr_src[p + 1];
    float n0 = csr_norm[p], n1 = csr_norm[p + 1];
    uint v0 = *(const uint*)&h[(size_t)s0 * IN + ch0];
    uint v1 = *(const uint*)&h[(size_t)s1 * IN + ch0];
    lo[0] = fmaf(n0, bf_lo(v0), lo[0]); hi[0] = fmaf(n0, bf_hi(v0), hi[0]);
    lo[1] = fmaf(n1, bf_lo(v1), lo[1]); hi[1] = fmaf(n1, bf_hi(v1), hi[1]);
  }
  if (p < e) {
    float n0 = csr_norm[p];
    uint v0 = *(const uint*)&h[(size_t)csr_src[p] * IN + ch0];
    lo[2] = fmaf(n0, bf_lo(v0), lo[2]); hi[2] = fmaf(n0, bf_hi(v0), hi[2]);
  }
  float r0 = ((lo[0] + lo[1]) + (lo[2] + lo[3])) + ((lo[4] + lo[5]) + (lo[6] + lo[7]));
  float r1 = ((hi[0] + hi[1]) + (hi[2] + hi[3])) + ((hi[4] + hi[5]) + (hi[6] + hi[7]));
  if (MODE == 1) {
    uint xv = *(const uint*)&xb[(size_t)node * IN + ch0];
    r0 = 2.f * r0 - bf_lo(xv);
    r1 = 2.f * r1 - bf_hi(xv);
  }
  uint packed = (uint)f2bf(r0) | ((uint)f2bf(r1) << 16);
  if (MODE == 0)
    *(uint*)&out_lin[(size_t)node * IN + ch0] = packed;
  *(uint*)&out_pk[pk_idx(node, ch0)] = packed;   // ch0 even -> uint-aligned in 8-chunk
}

// ---------------- fused MFMA GEMM: s1,s2,s3 ----------------
// grid = (7 tile-pairs [x, fastest], 391 M-tiles [y]); block = 256 (4 waves x 32 rows).
// A pre-packed in frag order; B pre-packed; C/D: row=(l>>4)*4+r, col=l&15.

__global__ __launch_bounds__(256) void k_gemm_mfma(
    const ushort* __restrict__ xp, const ushort* __restrict__ t1p, const ushort* __restrict__ t2p,
    const ushort* __restrict__ wpack,
    const float* __restrict__ b1v, const float* __restrict__ b2v, const float* __restrict__ b3v,
    float* __restrict__ out, int n) {
  int lane = threadIdx.x & 63;
  int wave = threadIdx.x >> 6;
  int row0 = blockIdx.y * MT + wave * 32;
  int rt0 = (row0 >> 4);

  // load A fragments (coalesced 1KB per instruction)
  bf16x8 a[3][2][4];
  const ushort* mats[3] = {xp, t1p, t2p};
#pragma unroll
  for (int m = 0; m < 3; ++m) {
#pragma unroll
    for (int g = 0; g < 2; ++g) {
#pragma unroll
      for (int kk = 0; kk < 4; ++kk) {
        size_t fi = ((size_t)(rt0 + g) * 4 + kk) * 512 + (size_t)lane * 8;
        a[m][g][kk] = __builtin_bit_cast(bf16x8, *(const ushort8*)&mats[m][fi]);
      }
    }
  }

  long NS = (long)n * OUT;
  float* out1 = out;
  float* out2 = out + NS;
  float* out3 = out + 2 * NS;

#pragma unroll
  for (int ti = 0; ti < 2; ++ti) {
    int t = blockIdx.x * 2 + ti;
    if (t >= NT) break;
    int col = t * 16 + (lane & 15);
    bool colok = col < OUT;
    int colc = colok ? col : 0;

    // ---- s1 = x @ w10 + b1 ----
    {
      float bias = colok ? b1v[colc] : 0.f;
      f32x4 acc0 = {bias, bias, bias, bias}, acc1 = acc0;
#pragma unroll
      for (int kk = 0; kk < 4; ++kk) {
        bf16x8 b = __builtin_bit_cast(bf16x8,
            *(const ushort8*)&wpack[(((size_t)(0 * NT + t) * 4 + kk) * 64 + lane) * 8]);
        acc0 = __builtin_amdgcn_mfma_f32_16x16x32_bf16(a[0][0][kk], b, acc0, 0, 0, 0);
        acc1 = __builtin_amdgcn_mfma_f32_16x16x32_bf16(a[0][1][kk], b, acc1, 0, 0, 0);
      }
      if (colok) {
#pragma unroll
        for (int r = 0; r < 4; ++r) {
          int ra = row0 + (lane >> 4) * 4 + r;
          if (ra < n) out1[(long)ra * OUT + col] = acc0[r];
          int rb = ra + 16;
          if (rb < n) out1[(long)rb * OUT + col] = acc1[r];
        }
      }
    }
    // ---- s2 = x @ w20 + tx1 @ w21 + b2 ----
    {
      float bias = colok ? b2v[colc] : 0.f;
      f32x4 acc0 = {bias, bias, bias, bias}, acc1 = acc0;
#pragma unroll
      for (int kk = 0; kk < 4; ++kk) {
        bf16x8 b = __builtin_bit_cast(bf16x8,
            *(const ushort8*)&wpack[(((size_t)(1 * NT + t) * 4 + kk) * 64 + lane) * 8]);
        acc0 = __builtin_amdgcn_mfma_f32_16x16x32_bf16(a[0][0][kk], b, acc0, 0, 0, 0);
        acc1 = __builtin_amdgcn_mfma_f32_16x16x32_bf16(a[0][1][kk], b, acc1, 0, 0, 0);
      }
#pragma unroll
      for (int kk = 0; kk < 4; ++kk) {
        bf16x8 b = __builtin_bit_cast(bf16x8,
            *(const ushort8*)&wpack[(((size_t)(2 * NT + t) * 4 + kk) * 64 + lane) * 8]);
        acc0 = __builtin_amdgcn_mfma_f32_16x16x32_bf16(a[1][0][kk], b, acc0, 0, 0, 0);
        acc1 = __builtin_amdgcn_mfma_f32_16x16x32_bf16(a[1][1][kk], b, acc1, 0, 0, 0);
      }
      if (colok) {
#pragma unroll
        for (int r = 0; r < 4; ++r) {
          int ra = row0 + (lane >> 4) * 4 + r;
          if (ra < n) out2[(long)ra * OUT + col] = acc0[r];
          int rb = ra + 16;
          if (rb < n) out2[(long)rb * OUT + col] = acc1[r];
        }
      }
    }
    // ---- s3 = x @ w30 + tx1 @ w31 + tx2 @ w32 + b3 ----
    {
      float bias = colok ? b3v[colc] : 0.f;
      f32x4 acc0 = {bias, bias, bias, bias}, acc1 = acc0;
#pragma unroll
      for (int m = 0; m < 3; ++m) {
#pragma unroll
        for (int kk = 0; kk < 4; ++kk) {
          bf16x8 b = __builtin_bit_cast(bf16x8,
              *(const ushort8*)&wpack[(((size_t)((3 + m) * NT + t) * 4 + kk) * 64 + lane) * 8]);
          acc0 = __builtin_amdgcn_mfma_f32_16x16x32_bf16(a[m][0][kk], b, acc0, 0, 0, 0);
          acc1 = __builtin_amdgcn_mfma_f32_16x16x32_bf16(a[m][1][kk], b, acc1, 0, 0, 0);
        }
      }
      if (colok) {
#pragma unroll
        for (int r = 0; r < 4; ++r) {
          int ra = row0 + (lane >> 4) * 4 + r;
          if (ra < n) out3[(long)ra * OUT + col] = acc0[r];
          int rb = ra + 16;
          if (rb < n) out3[(long)rb * OUT + col] = acc1[r];
        }
      }
    }
  }
}

// ---------------- launch ----------------

extern "C" void kernel_launch(void* const* d_in, const int* in_sizes, int n_in,
                              void* d_out, int out_size, void* d_ws, size_t ws_size,
                              hipStream_t stream) {
  const float* x   = (const float*)d_in[0];
  const int*   ei  = (const int*)d_in[1];
  const float* ew  = (const float*)d_in[2];
  const float* w10 = (const float*)d_in[3];
  const float* b1  = (const float*)d_in[4];
  const float* w20 = (const float*)d_in[5];
  const float* w21 = (const float*)d_in[6];
  const float* b2  = (const float*)d_in[7];
  const float* w30 = (const float*)d_in[8];
  const float* w31 = (const float*)d_in[9];
  const float* w32 = (const float*)d_in[10];
  const float* b3  = (const float*)d_in[11];
  float* out = (float*)d_out;

  int N = in_sizes[0] / IN;
  int E = in_sizes[2];
  const int* src = ei;
  const int* dst = ei + E;

  int mtiles = (N + MT - 1) / MT;           // 391
  size_t prow = (size_t)mtiles * MT;        // 50048 padded rows
  size_t pksz = prow * IN * 2;              // bytes per packed matrix

  char* ws = (char*)d_ws;
  size_t off = 0;
  auto alloc = [&](size_t bytes) {
    void* p = ws + off;
    off = (off + bytes + 15) & ~(size_t)15;
    return p;
  };
  // deg, cnt, cursor contiguous -> single memset
  float* deg      = (float*)alloc((size_t)N * 4);
  int*   cnt      = (int*)alloc((size_t)N * 4);
  int*   cursor   = (int*)alloc((size_t)N * 4);
  int*   offs     = (int*)alloc(((size_t)N + 1) * 4);
  int*   csr_src  = (int*)alloc((size_t)E * 4);
  float* csr_norm = (float*)alloc((size_t)E * 4);
  int*   bsum     = (int*)alloc(256 * 4);
  ushort* xb      = (ushort*)alloc((size_t)N * IN * 2);   // linear
  ushort* tx1b    = (ushort*)alloc((size_t)N * IN * 2);   // linear
  ushort* xp      = (ushort*)alloc(pksz);                 // packed
  ushort* t1p     = (ushort*)alloc(pksz);
  ushort* t2p     = (ushort*)alloc(pksz);
  ushort* wpack   = (ushort*)alloc((size_t)6 * NT * 4 * 64 * 8 * 2);

  hipMemsetAsync(deg, 0, (size_t)3 * N * 4, stream);   // deg + cnt + cursor

  const int tb = 256;
  int ge = (E + tb - 1) / tb;
  int nb = (N + 255) / 256;

  long totx = (long)N * IN;
  int cast_blocks = (int)((totx / 8 + tb - 1) / tb);
  int wp_blocks = (6 * NT * 4 * 64 + tb - 1) / tb;

  k_deg_cnt<<<ge, tb, 0, stream>>>(src, dst, ew, deg, cnt, E);
  k_dis_scan<<<nb, 256, 0, stream>>>(deg, cnt, offs, bsum, N);
  k_scan_b<<<1, 256, 0, stream>>>(bsum, nb);
  k_scan_c<<<nb, 256, 0, stream>>>(offs, bsum, N, E);
  k_fill<<<ge, tb, 0, stream>>>(src, dst, ew, deg, offs, cursor, csr_src, csr_norm, E);
  k_cast_pack<<<cast_blocks + wp_blocks, tb, 0, stream>>>(
      x, xb, xp, cast_blocks, totx, w10, w20, w21, w30, w31, w32, wpack);

  int gblk = (N + 3) / 4;
  k_gather<0><<<gblk, 256, 0, stream>>>(xb, xb, csr_src, csr_norm, offs, tx1b, t1p, N);
  k_gather<1><<<gblk, 256, 0, stream>>>(tx1b, xb, csr_src, csr_norm, offs, nullptr, t2p, N);

  dim3 gg((NT + 1) / 2, mtiles);   // x = tile-pair (fastest), y = M-tile
  k_gemm_mfma<<<gg, 256, 0, stream>>>(xp, t1p, t2p, wpack, b1, b2, b3, out, N);
}

// Round 5
// 288.719 us; speedup vs baseline: 2.0931x; 1.0295x over previous
//
#include <hip/hip_runtime.h>

#define IN 128
#define OUT 200
#define NT 13            // ceil(200/16) col-tiles
#define MT 64            // M rows per GEMM block (4 waves x 16 rows)

typedef __bf16 bf16x8 __attribute__((ext_vector_type(8)));
typedef float f32x4 __attribute__((ext_vector_type(4)));
typedef unsigned short ushort;
typedef ushort ushort8 __attribute__((ext_vector_type(8)));
typedef unsigned int uint;

__device__ inline ushort f2bf(float f) {          // RNE f32 -> bf16 bits
  uint b = __float_as_uint(f);
  return (ushort)((b + 0x7FFFu + ((b >> 16) & 1u)) >> 16);
}
__device__ inline float bf_lo(uint v) { return __uint_as_float(v << 16); }
__device__ inline float bf_hi(uint v) { return __uint_as_float(v & 0xFFFF0000u); }

// packed A layout: for (row r, ch k): rt=r>>4, lr=r&15, kk=k>>5, hi=(k&31)>>3, j=k&7
// ushort index = ((rt*4 + kk)*64 + hi*16 + lr)*8 + j        (512 ushorts per (rt,kk) frag)
__device__ inline size_t pk_idx(int row, int ch) {
  int rt = row >> 4, lr = row & 15, kk = ch >> 5, hi = (ch & 31) >> 3;
  return ((size_t)(rt * 4 + kk) * 64 + hi * 16 + lr) * 8 + (ch & 7);
}

// ---------------- graph preprocessing ----------------

__global__ void k_deg_cnt(const int* __restrict__ src, const int* __restrict__ dst,
                          const float* __restrict__ w, float* __restrict__ deg,
                          int* __restrict__ cnt, int E) {
  int e = blockIdx.x * blockDim.x + threadIdx.x;
  if (e >= E) return;
  atomicAdd(&deg[src[e]], w[e]);
  atomicAdd(&cnt[dst[e]], 1);
}

// dis (in-place on deg) + block-level exclusive scan of cnt
__global__ void k_dis_scan(float* __restrict__ deg, const int* __restrict__ cnt,
                           int* __restrict__ offs, int* __restrict__ bsum, int n) {
  __shared__ int s[256];
  int t = threadIdx.x;
  int i = blockIdx.x * 256 + t;
  if (i < n) {
    float d = deg[i];
    deg[i] = d > 0.f ? rsqrtf(d) : 0.f;
  }
  int v = (i < n) ? cnt[i] : 0;
  s[t] = v;
  __syncthreads();
  for (int o = 1; o < 256; o <<= 1) {
    int a = (t >= o) ? s[t - o] : 0;
    __syncthreads();
    s[t] += a;
    __syncthreads();
  }
  if (i < n) offs[i] = s[t] - v;
  if (t == 255) bsum[blockIdx.x] = s[255];
}

// merged: each block computes its own prefix of bsum, then offsets its slice
__global__ void k_scan_c2(int* __restrict__ offs, const int* __restrict__ bsum,
                          int n, int E) {
  __shared__ int red[256];
  int t = threadIdx.x;
  int partial = 0;
  for (int i = t; i < (int)blockIdx.x; i += 256) partial += bsum[i];
  red[t] = partial;
  __syncthreads();
  for (int o = 128; o > 0; o >>= 1) {
    if (t < o) red[t] += red[t + o];
    __syncthreads();
  }
  int base = red[0];
  int i = blockIdx.x * 256 + t;
  if (i < n) offs[i] += base;
  if (i == 0) offs[n] = E;
}

// fill CSR with norm computed inline: norm = -dis[src]*w*dis[dst]
__global__ void k_fill(const int* __restrict__ src, const int* __restrict__ dst,
                       const float* __restrict__ w, const float* __restrict__ dis,
                       const int* __restrict__ offs, int* __restrict__ cursor,
                       int* __restrict__ csr_src, float* __restrict__ csr_norm, int E) {
  int e = blockIdx.x * blockDim.x + threadIdx.x;
  if (e >= E) return;
  int sN = src[e], d = dst[e];
  int pos = offs[d] + atomicAdd(&cursor[d], 1);
  csr_src[pos] = sN;
  csr_norm[pos] = -dis[sN] * w[e] * dis[d];
}

// ---------------- fused cast(x) + pack(weights) ----------------

__global__ void k_cast_pack(const float* __restrict__ x, ushort* __restrict__ xb,
                            ushort* __restrict__ xp, int cast_blocks, long totx,
                            const float* __restrict__ w10, const float* __restrict__ w20,
                            const float* __restrict__ w21, const float* __restrict__ w30,
                            const float* __restrict__ w31, const float* __restrict__ w32,
                            ushort* __restrict__ wpack) {
  if (blockIdx.x < (unsigned)cast_blocks) {
    long i = ((long)blockIdx.x * blockDim.x + threadIdx.x) * 8;
    if (i >= totx) return;
    float4 a = *(const float4*)&x[i];
    float4 b = *(const float4*)&x[i + 4];
    ushort8 o;
    o[0] = f2bf(a.x); o[1] = f2bf(a.y); o[2] = f2bf(a.z); o[3] = f2bf(a.w);
    o[4] = f2bf(b.x); o[5] = f2bf(b.y); o[6] = f2bf(b.z); o[7] = f2bf(b.w);
    *(ushort8*)&xb[i] = o;
    int row = (int)(i >> 7), ch = (int)(i & 127);
    *(ushort8*)&xp[pk_idx(row, ch)] = o;   // pk_idx is 8-contiguous for ch%8==0
  } else {
    int gid = (blockIdx.x - cast_blocks) * blockDim.x + threadIdx.x;
    int total = 6 * NT * 4 * 64;
    if (gid >= total) return;
    int lane = gid & 63;
    int f = gid >> 6;
    int kk = f & 3;
    int t = (f >> 2) % NT;
    int m = f / (4 * NT);
    const float* w = (m == 0) ? w10 : (m == 1) ? w20 : (m == 2) ? w21
                   : (m == 3) ? w30 : (m == 4) ? w31 : w32;
    int col = t * 16 + (lane & 15);
    int kbase = kk * 32 + (lane >> 4) * 8;
    ushort8 o;
#pragma unroll
    for (int j = 0; j < 8; ++j)
      o[j] = (col < OUT) ? f2bf(w[(kbase + j) * OUT + col]) : (ushort)0;
    *(ushort8*)&wpack[(size_t)gid * 8] = o;
  }
}

// ---------------- gather propagation (bf16, fp32 accum, ILP 8) ----------------

template <int MODE>
__global__ void k_gather(const ushort* __restrict__ h, const ushort* __restrict__ xb,
                         const int* __restrict__ csr_src, const float* __restrict__ csr_norm,
                         const int* __restrict__ offs, ushort* __restrict__ out_lin,
                         ushort* __restrict__ out_pk, int n) {
  int node = blockIdx.x * 4 + (threadIdx.x >> 6);
  if (node >= n) return;
  int lane = threadIdx.x & 63;
  int ch0 = lane * 2;
  int s = offs[node], e = offs[node + 1];
  float lo[8], hi[8];
#pragma unroll
  for (int q = 0; q < 8; ++q) { lo[q] = 0.f; hi[q] = 0.f; }
  int p = s;
  for (; p + 7 < e; p += 8) {
    int si[8]; float nm[8]; uint v[8];
#pragma unroll
    for (int q = 0; q < 8; ++q) { si[q] = csr_src[p + q]; nm[q] = csr_norm[p + q]; }
#pragma unroll
    for (int q = 0; q < 8; ++q) v[q] = *(const uint*)&h[(size_t)si[q] * IN + ch0];
#pragma unroll
    for (int q = 0; q < 8; ++q) {
      lo[q] = fmaf(nm[q], bf_lo(v[q]), lo[q]);
      hi[q] = fmaf(nm[q], bf_hi(v[q]), hi[q]);
    }
  }
  for (; p + 1 < e; p += 2) {
    int s0 = csr_src[p], s1 = csr_src[p + 1];
    float n0 = csr_norm[p], n1 = csr_norm[p + 1];
    uint v0 = *(const uint*)&h[(size_t)s0 * IN + ch0];
    uint v1 = *(const uint*)&h[(size_t)s1 * IN + ch0];
    lo[0] = fmaf(n0, bf_lo(v0), lo[0]); hi[0] = fmaf(n0, bf_hi(v0), hi[0]);
    lo[1] = fmaf(n1, bf_lo(v1), lo[1]); hi[1] = fmaf(n1, bf_hi(v1), hi[1]);
  }
  if (p < e) {
    float n0 = csr_norm[p];
    uint v0 = *(const uint*)&h[(size_t)csr_src[p] * IN + ch0];
    lo[2] = fmaf(n0, bf_lo(v0), lo[2]); hi[2] = fmaf(n0, bf_hi(v0), hi[2]);
  }
  float r0 = ((lo[0] + lo[1]) + (lo[2] + lo[3])) + ((lo[4] + lo[5]) + (lo[6] + lo[7]));
  float r1 = ((hi[0] + hi[1]) + (hi[2] + hi[3])) + ((hi[4] + hi[5]) + (hi[6] + hi[7]));
  if (MODE == 1) {
    uint xv = *(const uint*)&xb[(size_t)node * IN + ch0];
    r0 = 2.f * r0 - bf_lo(xv);
    r1 = 2.f * r1 - bf_hi(xv);
  }
  uint packed = (uint)f2bf(r0) | ((uint)f2bf(r1) << 16);
  if (MODE == 0)
    *(uint*)&out_lin[(size_t)node * IN + ch0] = packed;
  *(uint*)&out_pk[pk_idx(node, ch0)] = packed;
}

// ---------------- fused MFMA GEMM: s1,s2,s3 ----------------
// grid = 782 M-blocks; block = 256 thr (4 waves x 16 rows). Each block owns its
// 64 A-rows exclusively (read once, coalesced) and loops all 13 col-tiles.
// B-frags (24KB/tile) are L1-deduped across the block's 4 waves.
// C/D: row = (l>>4)*4 + r, col = l&15.

__global__ __launch_bounds__(256) void k_gemm_mfma(
    const ushort* __restrict__ xp, const ushort* __restrict__ t1p, const ushort* __restrict__ t2p,
    const ushort* __restrict__ wpack,
    const float* __restrict__ b1v, const float* __restrict__ b2v, const float* __restrict__ b3v,
    float* __restrict__ out, int n) {
  int lane = threadIdx.x & 63;
  int wave = threadIdx.x >> 6;
  int row0 = blockIdx.x * MT + wave * 16;
  int rt = row0 >> 4;

  // load 12 A fragments (coalesced 1KB per instruction), reused for all 13 tiles
  bf16x8 a[3][4];
  const ushort* mats[3] = {xp, t1p, t2p};
#pragma unroll
  for (int m = 0; m < 3; ++m) {
#pragma unroll
    for (int kk = 0; kk < 4; ++kk) {
      size_t fi = ((size_t)rt * 4 + kk) * 512 + (size_t)lane * 8;
      a[m][kk] = __builtin_bit_cast(bf16x8, *(const ushort8*)&mats[m][fi]);
    }
  }

  long NS = (long)n * OUT;
  float* out1 = out;
  float* out2 = out + NS;
  float* out3 = out + 2 * NS;

  for (int t = 0; t < NT; ++t) {
    int col = t * 16 + (lane & 15);
    bool colok = col < OUT;
    int colc = colok ? col : 0;
    float bb1 = colok ? b1v[colc] : 0.f;
    float bb2 = colok ? b2v[colc] : 0.f;
    float bb3 = colok ? b3v[colc] : 0.f;
    f32x4 c1 = {bb1, bb1, bb1, bb1};
    f32x4 c2 = {bb2, bb2, bb2, bb2};
    f32x4 c3 = {bb3, bb3, bb3, bb3};
#pragma unroll
    for (int kk = 0; kk < 4; ++kk) {
      const size_t base = ((size_t)t * 4 + kk) * 64 * 8 + (size_t)lane * 8;
      const size_t mstep = (size_t)NT * 4 * 64 * 8;
      bf16x8 b10 = __builtin_bit_cast(bf16x8, *(const ushort8*)&wpack[base]);
      bf16x8 b20 = __builtin_bit_cast(bf16x8, *(const ushort8*)&wpack[base + mstep]);
      bf16x8 b21 = __builtin_bit_cast(bf16x8, *(const ushort8*)&wpack[base + 2 * mstep]);
      bf16x8 b30 = __builtin_bit_cast(bf16x8, *(const ushort8*)&wpack[base + 3 * mstep]);
      bf16x8 b31 = __builtin_bit_cast(bf16x8, *(const ushort8*)&wpack[base + 4 * mstep]);
      bf16x8 b32 = __builtin_bit_cast(bf16x8, *(const ushort8*)&wpack[base + 5 * mstep]);
      c1 = __builtin_amdgcn_mfma_f32_16x16x32_bf16(a[0][kk], b10, c1, 0, 0, 0);
      c2 = __builtin_amdgcn_mfma_f32_16x16x32_bf16(a[0][kk], b20, c2, 0, 0, 0);
      c2 = __builtin_amdgcn_mfma_f32_16x16x32_bf16(a[1][kk], b21, c2, 0, 0, 0);
      c3 = __builtin_amdgcn_mfma_f32_16x16x32_bf16(a[0][kk], b30, c3, 0, 0, 0);
      c3 = __builtin_amdgcn_mfma_f32_16x16x32_bf16(a[1][kk], b31, c3, 0, 0, 0);
      c3 = __builtin_amdgcn_mfma_f32_16x16x32_bf16(a[2][kk], b32, c3, 0, 0, 0);
    }
    if (colok) {
      int rbase = row0 + (lane >> 4) * 4;
#pragma unroll
      for (int r = 0; r < 4; ++r) {
        int ra = rbase + r;
        if (ra < n) {
          out1[(long)ra * OUT + col] = c1[r];
          out2[(long)ra * OUT + col] = c2[r];
          out3[(long)ra * OUT + col] = c3[r];
        }
      }
    }
  }
}

// ---------------- launch ----------------

extern "C" void kernel_launch(void* const* d_in, const int* in_sizes, int n_in,
                              void* d_out, int out_size, void* d_ws, size_t ws_size,
                              hipStream_t stream) {
  const float* x   = (const float*)d_in[0];
  const int*   ei  = (const int*)d_in[1];
  const float* ew  = (const float*)d_in[2];
  const float* w10 = (const float*)d_in[3];
  const float* b1  = (const float*)d_in[4];
  const float* w20 = (const float*)d_in[5];
  const float* w21 = (const float*)d_in[6];
  const float* b2  = (const float*)d_in[7];
  const float* w30 = (const float*)d_in[8];
  const float* w31 = (const float*)d_in[9];
  const float* w32 = (const float*)d_in[10];
  const float* b3  = (const float*)d_in[11];
  float* out = (float*)d_out;

  int N = in_sizes[0] / IN;
  int E = in_sizes[2];
  const int* src = ei;
  const int* dst = ei + E;

  int mtiles = (N + MT - 1) / MT;           // 782
  size_t prow = (size_t)mtiles * MT;        // 50048 padded rows
  size_t pksz = prow * IN * 2;              // bytes per packed matrix

  char* ws = (char*)d_ws;
  size_t off = 0;
  auto alloc = [&](size_t bytes) {
    void* p = ws + off;
    off = (off + bytes + 15) & ~(size_t)15;
    return p;
  };
  float* deg      = (float*)alloc((size_t)N * 4);
  int*   cnt      = (int*)alloc((size_t)N * 4);
  int*   cursor   = (int*)alloc((size_t)N * 4);
  int*   offs     = (int*)alloc(((size_t)N + 1) * 4);
  int*   csr_src  = (int*)alloc((size_t)E * 4);
  float* csr_norm = (float*)alloc((size_t)E * 4);
  int*   bsum     = (int*)alloc(256 * 4);
  ushort* xb      = (ushort*)alloc((size_t)N * IN * 2);   // linear
  ushort* tx1b    = (ushort*)alloc((size_t)N * IN * 2);   // linear
  ushort* xp      = (ushort*)alloc(pksz);                 // packed
  ushort* t1p     = (ushort*)alloc(pksz);
  ushort* t2p     = (ushort*)alloc(pksz);
  ushort* wpack   = (ushort*)alloc((size_t)6 * NT * 4 * 64 * 8 * 2);

  hipMemsetAsync(deg, 0, (size_t)3 * N * 4, stream);   // deg + cnt + cursor

  const int tb = 256;
  int ge = (E + tb - 1) / tb;
  int nb = (N + 255) / 256;

  long totx = (long)N * IN;
  int cast_blocks = (int)((totx / 8 + tb - 1) / tb);
  int wp_blocks = (6 * NT * 4 * 64 + tb - 1) / tb;

  k_deg_cnt<<<ge, tb, 0, stream>>>(src, dst, ew, deg, cnt, E);
  k_dis_scan<<<nb, 256, 0, stream>>>(deg, cnt, offs, bsum, N);
  k_scan_c2<<<nb, 256, 0, stream>>>(offs, bsum, N, E);
  k_fill<<<ge, tb, 0, stream>>>(src, dst, ew, deg, offs, cursor, csr_src, csr_norm, E);
  k_cast_pack<<<cast_blocks + wp_blocks, tb, 0, stream>>>(
      x, xb, xp, cast_blocks, totx, w10, w20, w21, w30, w31, w32, wpack);

  int gblk = (N + 3) / 4;
  k_gather<0><<<gblk, 256, 0, stream>>>(xb, xb, csr_src, csr_norm, offs, tx1b, t1p, N);
  k_gather<1><<<gblk, 256, 0, stream>>>(tx1b, xb, csr_src, csr_norm, offs, nullptr, t2p, N);

  k_gemm_mfma<<<mtiles, 256, 0, stream>>>(xp, t1p, t2p, wpack, b1, b2, b3, out, N);
}